// Round 1
// 94.365 us; speedup vs baseline: 1.0316x; 1.0316x over previous
//
#include <hip/hip_runtime.h>
#include <hip/hip_bf16.h>

#define BATCH 8
#define SEQ   2048
#define DIM   64
#define TSPLIT 4                     // r17: 8->4 halves nbuf/dbuf partial traffic
#define NIT   (SEQ / TSPLIT / 64)    // 8 key-tiles of 64 per block

typedef __attribute__((ext_vector_type(8))) short short8;
typedef __attribute__((ext_vector_type(4))) float floatx4;

// fast f32->bf16: +0x8000 then truncate (<=0.5ulp + 2^-17 bias; bf16 already 0.4% quant)
static __device__ __forceinline__ unsigned short f2bf(float x) {
    union { float f; unsigned u; } v; v.f = x;
    return (unsigned short)((v.u + 0x8000u) >> 16);
}
static __device__ __forceinline__ float bf2f(unsigned short u) {
    union { unsigned u; float f; } v; v.u = (unsigned)u << 16;
    return v.f;
}

#if __has_builtin(__builtin_amdgcn_sqrtf)
#define FSQRT(x) __builtin_amdgcn_sqrtf(x)
#else
#define FSQRT(x) sqrtf(x)
#endif
#if __has_builtin(__builtin_amdgcn_exp2f)
#define FEXP2(x) __builtin_amdgcn_exp2f(x)
#else
#define FEXP2(x) exp2f(x)
#endif

// log2(e)^2: folded into Qb/q2/k2 so wgt = exp2(-sqrt(seeded-MFMA result))
#define C2 2.0813689810056077f

// async global->LDS DMA, 16 B/lane; LDS dest = wave-uniform base + lane*16
static __device__ __forceinline__ void load_lds16(const void* g, void* l) {
    __builtin_amdgcn_global_load_lds(
        (const __attribute__((address_space(1))) void*)g,
        (__attribute__((address_space(3))) void*)l, 16, 0, 0);
}

// ---- fused prep ------------------------------------------------------------
// blocks [0,2048): Q/K bf16 cast, one float4/thread (single pass) + row norms.
//   Q holds -2*C2*q; q2/k2 hold C2*norm (folds the exp2 conversion into data).
//   K chunk-swizzled for the unpadded LDS tile.
// blocks [2048,2304): V -> Vt transpose (chunk-swizzled) + csum partials.
#define QK_BLK 2048
#define VT_BLK 256

__global__ __launch_bounds__(256) void prep_all(
        const float* __restrict__ Q, const float* __restrict__ K,
        const float* __restrict__ V,
        unsigned short* __restrict__ Qb, unsigned short* __restrict__ Kb,
        unsigned short* __restrict__ Vt,
        float* __restrict__ q2, float* __restrict__ k2,
        float* __restrict__ csum_part) {
    int bid = blockIdx.x;
    if (bid < QK_BLK) {
        const int NQ = BATCH * SEQ * (DIM / 4);   // 262144 float4s in Q
        int gid = bid * 256 + threadIdx.x;
        const float* src; unsigned short* db; float* dn; int idx; float scl; int swz;
        if (gid < NQ) { src = Q; db = Qb; dn = q2; idx = gid;      scl = -2.f * C2; swz = 0; }
        else          { src = K; db = Kb; dn = k2; idx = gid - NQ; scl =  1.f;      swz = 1; }
        float4 v = ((const float4*)src)[idx];
        float s = v.x * v.x + v.y * v.y + v.z * v.z + v.w * v.w;   // raw row norm
        ushort4 o;
        o.x = f2bf(v.x * scl); o.y = f2bf(v.y * scl);
        o.z = f2bf(v.z * scl); o.w = f2bf(v.w * scl);
        int row = idx >> 4, j = idx & 15;
        int jo  = swz ? (j ^ ((row & 7) << 1)) : j;   // 16B-chunk XOR swizzle
        ((ushort4*)db)[(row << 4) | jo] = o;
        s += __shfl_xor(s, 1); s += __shfl_xor(s, 2);
        s += __shfl_xor(s, 4); s += __shfl_xor(s, 8);
        if (j == 0) dn[row] = s * C2;
    } else {
        __shared__ float tile[64][65];
        __shared__ float psum[4][64];
        int vb = bid - QK_BLK;                    // vb = b*32 + tile
        int b  = vb >> 5;
        int t0 = (vb & 31) * 64;
        int i  = threadIdx.x;
        int d  = i & 63, g = i >> 6;
        float part = 0.f;
        #pragma unroll
        for (int p = 0; p < 16; ++p) {
            int tt = p * 4 + g;
            float v = V[((size_t)(b * SEQ + t0 + tt)) * DIM + d];
            tile[tt][d] = v;
            part += v;
        }
        psum[g][d] = part;
        __syncthreads();
        int tt = i & 63;
        #pragma unroll
        for (int p = 0; p < 16; ++p) {
            int dd = p * 4 + g;
            // chunk swizzle within the 64-key (128 B) slice
            Vt[((size_t)(b * DIM + dd)) * SEQ + t0 + (tt ^ ((dd & 7) << 3))] =
                f2bf(tile[tt][dd]);
        }
        if (i < 64)
            csum_part[vb * 64 + i] =
                psum[0][i] + psum[1][i] + psum[2][i] + psum[3][i];
    }
}

// ---- main: shifted-softmax gaussian attention ------------------------------
// LAUNCH BOUNDS LESSON (r4/r12/r13): min-waves >= 5 caps the unified
// VGPR+AGPR budget below this loop's ~90-reg need -> hot-loop scratch spill.
// (256,4) = cap 128, no spill.
// r17 STRUCTURE: double-buffered K/V tiles (40960 B LDS = exact 4 blocks/CU),
// ONE barrier per tile: barrier -> stage(next, alt buf) -> compute(cur).
// The barrier's implicit vmcnt(0) drain now lands a full compute phase after
// DMA issue -> L2 latency hidden (was: issue, immediate drain = serial stall).
// k2 moved out of LDS (exact-fit) to per-lane global loads, ping-pong
// prefetched one tile ahead (L1/L2-resident, +8 VGPR).
__global__ __launch_bounds__(256, 4) void gauss_attn(
        const unsigned short* __restrict__ Qb, const unsigned short* __restrict__ Kb,
        const unsigned short* __restrict__ Vt, const float* __restrict__ q2,
        const float* __restrict__ k2,
        unsigned short* __restrict__ nbuf, float* __restrict__ dbuf) {
    __shared__ __align__(16) struct {
        unsigned short Kt[2][64 * 64];   // 16 KB (K tiles, unpadded, swizzled)
        unsigned short Vv[2][64 * 64];   // 16 KB (V tiles, unpadded, swizzled)
        unsigned short P[4][16 * 64];    // 8 KB (per-wave P', chunk-swizzled)
    } sh;                                // = 40960 B exactly (160 KB / 4)

    const int bid   = blockIdx.x;                 // grid = 8 * 32 * 4
    const int ts    = bid & (TSPLIT - 1);         // key quarter (== XCD-local)
    const int qt    = (bid >> 2) & 31;            // 64-row q tile
    const int b     = bid >> 7;
    const int tid   = threadIdx.x;
    const int w     = tid >> 6;
    const int lane  = tid & 63;
    const int l15   = lane & 15;
    const int quad  = lane >> 4;
    const int qrow0 = qt * 64 + w * 16;           // this wave's 16 q-rows
    const int s7    = l15 & 7;                    // fragment de-swizzle key
    const int t00   = ts * (SEQ / TSPLIT);        // this block's 512 keys

    const size_t kbase = (size_t)b * SEQ * DIM;   // shorts
    const size_t vbase = (size_t)b * DIM * SEQ;

    // Q fragments (A operand, holds -2*C2*q): A[m=lane&15][k=quad*8+j]
    short8 qf0 = *(const short8*)(Qb + ((size_t)(b * SEQ + qrow0 + l15)) * DIM + quad * 8);
    short8 qf1 = *(const short8*)(Qb + ((size_t)(b * SEQ + qrow0 + l15)) * DIM + 32 + quad * 8);
    floatx4 q2v = *(const floatx4*)(q2 + b * SEQ + qrow0 + quad * 4);
    const float* k2g = k2 + b * SEQ + t00 + l15;  // per-lane k2 base

    floatx4 acc[4];
    #pragma unroll
    for (int nt = 0; nt < 4; ++nt) acc[nt] = (floatx4){0.f, 0.f, 0.f, 0.f};
    float dsum[4] = {0.f, 0.f, 0.f, 0.f};

    unsigned short* Pw = sh.P[w];

    // stage one 64-key tile (K rows + V(d) rows) into buffer bufi
    auto stage = [&](int bufi, int t0) {
        #pragma unroll
        for (int i = 0; i < 2; ++i) {
            int r = w * 16 + i * 8;
            load_lds16(Kb + kbase + (size_t)(t0 + r + (lane >> 3)) * DIM + (lane & 7) * 8,
                       &sh.Kt[bufi][r * 64]);
            load_lds16(Vt + vbase + (size_t)(r + (lane >> 3)) * SEQ + t0 + (lane & 7) * 8,
                       &sh.Vv[bufi][r * 64]);
        }
    };

    // QK^T + score transform + P store + P'V for one resident tile
    auto compute = [&](const unsigned short* Kt, const unsigned short* Vv,
                       const float* k2c) {
        #pragma unroll
        for (int nt = 0; nt < 4; ++nt) {
            short8 kf0 = *(const short8*)&Kt[(nt * 16 + l15) * 64 + ((quad ^ s7) << 3)];
            short8 kf1 = *(const short8*)&Kt[(nt * 16 + l15) * 64 + (((4 | quad) ^ s7) << 3)];
            float k2n = k2c[nt];
            floatx4 sc;
            #pragma unroll
            for (int r = 0; r < 4; ++r) sc[r] = q2v[r] + k2n;   // seed C2*(q2+k2)
            sc = __builtin_amdgcn_mfma_f32_16x16x32_bf16(qf0, kf0, sc, 0, 0, 0);
            sc = __builtin_amdgcn_mfma_f32_16x16x32_bf16(qf1, kf1, sc, 0, 0, 0);
            #pragma unroll
            for (int r = 0; r < 4; ++r) {
                float d2s = fmaxf(sc[r], 0.f);                 // C2 * d2
                float wgt = FEXP2(-FSQRT(d2s));                // exp(-dist)
                // expm1(wgt) quadratic; wgt < 3e-3 at 5 sigma -> rel err < 2e-6
                float pv = wgt * fmaf(wgt, 0.5f, 1.f);
                dsum[r] += pv;
                int row = quad * 4 + r;
                // chunk-swizzled P store: chunk (nt*2 | l15>>3) -> ^(row&7)
                Pw[row * 64 + ((((nt << 1) | (l15 >> 3)) ^ (row & 7)) << 3) + (l15 & 7)]
                    = f2bf(pv);
            }
        }
        // ---- P'V from LDS tiles (pf read de-swizzles with l15&7) ----
        #pragma unroll
        for (int tc = 0; tc < 2; ++tc) {
            short8 pf = *(const short8*)&Pw[l15 * 64 + (((tc * 4 + quad) ^ s7) << 3)];
            #pragma unroll
            for (int nt = 0; nt < 4; ++nt) {
                short8 vf = *(const short8*)
                    &Vv[(nt * 16 + l15) * 64 + ((((tc << 2) | quad) ^ s7) << 3)];
                acc[nt] = __builtin_amdgcn_mfma_f32_16x16x32_bf16(pf, vf, acc[nt], 0, 0, 0);
            }
        }
    };

    // prologue: stage tile 0 + its k2
    stage(0, t00);
    float k2a[4], k2b_[4];
    #pragma unroll
    for (int nt = 0; nt < 4; ++nt) k2a[nt] = k2g[nt * 16];

    #pragma unroll 1
    for (int itp = 0; itp < NIT / 2; ++itp) {
        const int t0e = t00 + itp * 128;
        __syncthreads();                 // even tile DMA drained (all waves)
        stage(1, t0e + 64);              // prefetch odd tile under compute
        #pragma unroll
        for (int nt = 0; nt < 4; ++nt) k2b_[nt] = k2g[itp * 128 + 64 + nt * 16];
        compute(sh.Kt[0], sh.Vv[0], k2a);

        __syncthreads();                 // odd tile DMA drained (all waves)
        if (itp < NIT / 2 - 1) {
            stage(0, t0e + 128);         // prefetch next even tile
            #pragma unroll
            for (int nt = 0; nt < 4; ++nt) k2a[nt] = k2g[itp * 128 + 128 + nt * 16];
        }
        compute(sh.Kt[1], sh.Vv[1], k2b_);
    }

    // ---- partial epilogue: plain bf16 stores to this split's buffers ----
    #pragma unroll
    for (int r = 0; r < 4; ++r) {
        dsum[r] += __shfl_xor(dsum[r], 1);
        dsum[r] += __shfl_xor(dsum[r], 2);
        dsum[r] += __shfl_xor(dsum[r], 4);
        dsum[r] += __shfl_xor(dsum[r], 8);
    }
    unsigned short* nb = nbuf + (size_t)ts * (BATCH * SEQ * DIM);
    #pragma unroll
    for (int nt = 0; nt < 4; ++nt) {
        #pragma unroll
        for (int r = 0; r < 4; ++r) {
            nb[((size_t)(b * SEQ + qrow0 + quad * 4 + r)) * DIM + nt * 16 + l15] =
                f2bf(acc[nt][r]);
        }
    }
    if (l15 == 0) {
        #pragma unroll
        for (int r = 0; r < 4; ++r)
            dbuf[ts * (BATCH * SEQ) + b * SEQ + qrow0 + quad * 4 + r] = dsum[r];
    }
}

// ---- finalize: out = (sum_ts nbuf + csum) / (S + sum_ts dbuf) --------------
// csum reduced block-cooperatively through LDS (one 8KB pass per block).
__global__ __launch_bounds__(256) void finalize(
        const unsigned short* __restrict__ nbuf, const float* __restrict__ dbuf,
        const float* __restrict__ csum_part, float* __restrict__ out) {
    __shared__ float psh[4][64];
    __shared__ float csh[64];
    int bid = blockIdx.x, tid = threadIdx.x;     // 1024 blocks; 16 rows/block
    int b = bid >> 7;                            // all rows in a block share b
    {
        int g = tid >> 6, d = tid & 63;
        float cp = 0.f;
        #pragma unroll
        for (int p = 0; p < 8; ++p)
            cp += csum_part[(b * 32 + g * 8 + p) * 64 + d];
        psh[g][d] = cp;
    }
    __syncthreads();
    if (tid < 64)
        csh[tid] = psh[0][tid] + psh[1][tid] + psh[2][tid] + psh[3][tid];
    __syncthreads();

    int gid = bid * 256 + tid;                   // one float4 of d per thread
    int row = gid >> 4;                          // b*SEQ + s
    int dq  = gid & 15;
    float den = 2048.f;
    #pragma unroll
    for (int t = 0; t < TSPLIT; ++t) den += dbuf[t * (BATCH * SEQ) + row];
    float rcp = 1.f / den;
    float4 n = *(const float4*)&csh[dq * 4];
    #pragma unroll
    for (int t = 0; t < TSPLIT; ++t) {
        ushort4 p = *(const ushort4*)(nbuf + (size_t)t * (BATCH * SEQ * DIM)
                                           + (size_t)row * DIM + dq * 4);
        n.x += bf2f(p.x); n.y += bf2f(p.y); n.z += bf2f(p.z); n.w += bf2f(p.w);
    }
    float4 o = {n.x * rcp, n.y * rcp, n.z * rcp, n.w * rcp};
    *(float4*)(out + (size_t)row * DIM + dq * 4) = o;
}

extern "C" void kernel_launch(void* const* d_in, const int* in_sizes, int n_in,
                              void* d_out, int out_size, void* d_ws, size_t ws_size,
                              hipStream_t stream) {
    const float* Q = (const float*)d_in[0];
    const float* K = (const float*)d_in[1];
    const float* V = (const float*)d_in[2];
    float* out = (float*)d_out;

    char* ws = (char*)d_ws;                       // ws_size = 256 MiB
    unsigned short* Qb = (unsigned short*)(ws);                        // 2 MB
    unsigned short* Kb = (unsigned short*)(ws + (2u << 20));           // 2 MB (swizzled)
    unsigned short* Vt = (unsigned short*)(ws + (4u << 20));           // 2 MB (swizzled)
    float* q2     = (float*)(ws + (6u << 20));                         // 64 KB
    float* k2     = (float*)(ws + (6u << 20) + (64u << 10));           // 64 KB
    float* cpart  = (float*)(ws + (6u << 20) + (128u << 10));          // 64 KB
    float* dbuf   = (float*)(ws + (6u << 20) + (192u << 10));          // 256 KB (4 splits)
    unsigned short* nbuf = (unsigned short*)(ws + (7u << 20));         // 8 MB (bf16, 4 splits)

    prep_all<<<QK_BLK + VT_BLK, 256, 0, stream>>>(
        Q, K, V, Qb, Kb, Vt, q2, k2, cpart);
    gauss_attn<<<BATCH * 32 * TSPLIT, 256, 0, stream>>>(
        Qb, Kb, Vt, q2, k2, nbuf, dbuf);
    finalize<<<(BATCH * SEQ * DIM / 4) / 256, 256, 0, stream>>>(
        nbuf, dbuf, cpart, out);
}

// Round 2
// 94.049 us; speedup vs baseline: 1.0351x; 1.0034x over previous
//
#include <hip/hip_runtime.h>
#include <hip/hip_bf16.h>

#define BATCH 8
#define SEQ   2048
#define DIM   64
#define TSPLIT 4                     // r17: 4-way key split; each XCD sees one ts

typedef __attribute__((ext_vector_type(8))) short short8;
typedef __attribute__((ext_vector_type(4))) float floatx4;
typedef __attribute__((ext_vector_type(16))) float f32x16;
typedef __attribute__((ext_vector_type(2))) unsigned int uintx2;

// fast f32->bf16: +0x8000 then truncate (<=0.5ulp + 2^-17 bias; bf16 already 0.4% quant)
static __device__ __forceinline__ unsigned short f2bf(float x) {
    union { float f; unsigned u; } v; v.f = x;
    return (unsigned short)((v.u + 0x8000u) >> 16);
}
static __device__ __forceinline__ float bf2f(unsigned short u) {
    union { unsigned u; float f; } v; v.u = (unsigned)u << 16;
    return v.f;
}
// pack two f32 -> one u32 of 2 bf16 (hi<<16 | lo), round-add then byte-select
static __device__ __forceinline__ unsigned pkbf(unsigned hi_, unsigned lo_) {
#if __has_builtin(__builtin_amdgcn_perm)
    return __builtin_amdgcn_perm(hi_ + 0x8000u, lo_ + 0x8000u, 0x07060302u);
#else
    return ((lo_ + 0x8000u) >> 16) | ((hi_ + 0x8000u) & 0xffff0000u);
#endif
}

#if __has_builtin(__builtin_amdgcn_sqrtf)
#define FSQRT(x) __builtin_amdgcn_sqrtf(x)
#else
#define FSQRT(x) sqrtf(x)
#endif
#if __has_builtin(__builtin_amdgcn_exp2f)
#define FEXP2(x) __builtin_amdgcn_exp2f(x)
#else
#define FEXP2(x) exp2f(x)
#endif

// log2(e)^2: folded into Qb/q2/k2 so wgt = exp2(-sqrt(seeded-MFMA result))
#define C2 2.0813689810056077f

// async global->LDS DMA, 16 B/lane; LDS dest = wave-uniform base + lane*16
static __device__ __forceinline__ void load_lds16(const void* g, void* l) {
    __builtin_amdgcn_global_load_lds(
        (const __attribute__((address_space(1))) void*)g,
        (__attribute__((address_space(3))) void*)l, 16, 0, 0);
}

// ---- fused prep ------------------------------------------------------------
// blocks [0,2048): Q/K bf16 cast, one float4/thread (single pass) + row norms.
//   Q holds -2*C2*q; q2/k2 hold C2*norm (folds the exp2 conversion into data).
//   K chunk-swizzled (16B chunk ^ (key&7)) for the unpadded LDS tile.
// blocks [2048,2304): V -> Vt transpose (chunk-swizzled) + csum partials.
#define QK_BLK 2048
#define VT_BLK 256

__global__ __launch_bounds__(256) void prep_all(
        const float* __restrict__ Q, const float* __restrict__ K,
        const float* __restrict__ V,
        unsigned short* __restrict__ Qb, unsigned short* __restrict__ Kb,
        unsigned short* __restrict__ Vt,
        float* __restrict__ q2, float* __restrict__ k2,
        float* __restrict__ csum_part) {
    int bid = blockIdx.x;
    if (bid < QK_BLK) {
        const int NQ = BATCH * SEQ * (DIM / 4);   // 262144 float4s in Q
        int gid = bid * 256 + threadIdx.x;
        const float* src; unsigned short* db; float* dn; int idx; float scl; int swz;
        if (gid < NQ) { src = Q; db = Qb; dn = q2; idx = gid;      scl = -2.f * C2; swz = 0; }
        else          { src = K; db = Kb; dn = k2; idx = gid - NQ; scl =  1.f;      swz = 1; }
        float4 v = ((const float4*)src)[idx];
        float s = v.x * v.x + v.y * v.y + v.z * v.z + v.w * v.w;   // raw row norm
        ushort4 o;
        o.x = f2bf(v.x * scl); o.y = f2bf(v.y * scl);
        o.z = f2bf(v.z * scl); o.w = f2bf(v.w * scl);
        int row = idx >> 4, j = idx & 15;
        int jo  = swz ? (j ^ ((row & 7) << 1)) : j;   // 16B-chunk XOR swizzle
        ((ushort4*)db)[(row << 4) | jo] = o;
        s += __shfl_xor(s, 1); s += __shfl_xor(s, 2);
        s += __shfl_xor(s, 4); s += __shfl_xor(s, 8);
        if (j == 0) dn[row] = s * C2;
    } else {
        __shared__ float tile[64][65];
        __shared__ float psum[4][64];
        int vb = bid - QK_BLK;                    // vb = b*32 + tile
        int b  = vb >> 5;
        int t0 = (vb & 31) * 64;
        int i  = threadIdx.x;
        int d  = i & 63, g = i >> 6;
        float part = 0.f;
        #pragma unroll
        for (int p = 0; p < 16; ++p) {
            int tt = p * 4 + g;
            float v = V[((size_t)(b * SEQ + t0 + tt)) * DIM + d];
            tile[tt][d] = v;
            part += v;
        }
        psum[g][d] = part;
        __syncthreads();
        int tt = i & 63;
        #pragma unroll
        for (int p = 0; p < 16; ++p) {
            int dd = p * 4 + g;
            // chunk swizzle within the 64-key (128 B) slice
            Vt[((size_t)(b * DIM + dd)) * SEQ + t0 + (tt ^ ((dd & 7) << 3))] =
                f2bf(tile[tt][dd]);
        }
        if (i < 64)
            csum_part[vb * 64 + i] =
                psum[0][i] + psum[1][i] + psum[2][i] + psum[3][i];
    }
}

// ---- main: shifted-softmax gaussian attention ------------------------------
// r18 STRUCTURE: 32x32x16 MFMA, SWAPPED operands (A=K rows=keys, B=Q cols=q).
//   - wave owns 32 q-rows x 64 keys/tile: LDS bytes/element ~halved vs 16x16,
//     MFMA instruction count/element halved.
//   - score layout: lane holds 16 keys for its single q (=lane&31) -> dsum is
//     ONE register, one shfl_xor(32) at the end.
//   - P packed to bf16x2 via v_perm, stored as ds_write_b64 into per-wave
//     32x64 tile (16B chunk ^ (q&7) swizzle) -> conflict-free b128 A-reads.
// Double-buffered K/V/k2 stage (r17): barrier -> stage(next) -> compute(cur);
// DMA latency hides under a full compute phase.
// launch_bounds (256,2): grid 512 = 2 blocks/CU (grid-limited), cap 256 VGPR
// -> zero spill risk (r4/r12/r13 lesson: tight caps spill the hot loop).
__global__ __launch_bounds__(256, 2) void gauss_attn(
        const unsigned short* __restrict__ Qb, const unsigned short* __restrict__ Kb,
        const unsigned short* __restrict__ Vt, const float* __restrict__ q2,
        const float* __restrict__ k2,
        unsigned short* __restrict__ nbuf, float* __restrict__ dbuf) {
    __shared__ __align__(16) struct {
        unsigned short Kt[2][64 * 64];   // 16 KB (K tiles, swizzled)
        unsigned short Vv[2][64 * 64];   // 16 KB (V tiles, d-major, swizzled)
        unsigned short P[4][32 * 64];    // 16 KB (per-wave P', chunk-swizzled)
        float k2sh[2][64];               // 512 B
    } sh;                                // = 49664 B -> 2 blocks/CU

    const int bid   = blockIdx.x;                 // grid = 8 * 16 * 4
    const int ts    = bid & 3;                    // key quarter (XCD-local)
    const int qt    = (bid >> 2) & 15;            // 128-row q tile
    const int b     = bid >> 6;
    const int tid   = threadIdx.x;
    const int w     = tid >> 6;
    const int lane  = tid & 63;
    const int l31   = lane & 31;
    const int hi    = lane >> 5;
    const int s7    = l31 & 7;                    // fragment de-swizzle key
    const int qrow0 = qt * 128 + w * 32;          // this wave's 32 q-rows
    const int t00   = ts * (SEQ / TSPLIT);        // this block's 512 keys

    const size_t kbase = (size_t)b * SEQ * DIM;   // shorts
    const size_t vbase = (size_t)b * DIM * SEQ;

    // Q fragments (B operand, holds -2*C2*q): B[n=l31][k=kk*16 + hi*8 + j]
    short8 qf[4];
    #pragma unroll
    for (int kk = 0; kk < 4; ++kk)
        qf[kk] = *(const short8*)(Qb + ((size_t)(b * SEQ + qrow0 + l31)) * DIM
                                     + kk * 16 + hi * 8);
    const float q2s = q2[b * SEQ + qrow0 + l31];  // C2*||q||^2 for this lane's q
    const float* k2g0 = k2 + b * SEQ;

    f32x16 acc[2];
    #pragma unroll
    for (int dt = 0; dt < 2; ++dt)
        #pragma unroll
        for (int r = 0; r < 16; ++r) acc[dt][r] = 0.f;
    float dsl = 0.f;

    unsigned short* Pw = sh.P[w];

    // stage one 64-key tile: K rows (keys), Vt rows (d), k2 slice
    auto stage = [&](int bufi, int t0) {
        #pragma unroll
        for (int i = 0; i < 2; ++i) {
            int r = w * 16 + i * 8;
            load_lds16(Kb + kbase + (size_t)(t0 + r + (lane >> 3)) * DIM + (lane & 7) * 8,
                       &sh.Kt[bufi][r * 64]);
            load_lds16(Vt + vbase + (size_t)(r + (lane >> 3)) * SEQ + t0 + (lane & 7) * 8,
                       &sh.Vv[bufi][r * 64]);
        }
        if (tid < 16) load_lds16(k2g0 + t0 + tid * 4, &sh.k2sh[bufi][0]);
    };

    // one resident 64-key tile: swapped QK^T + transform + packed P + P'V
    auto compute = [&](int bufi) {
        const unsigned short* Kt = sh.Kt[bufi];
        const unsigned short* Vv = sh.Vv[bufi];
        const float* k2c = sh.k2sh[bufi];
        #pragma unroll
        for (int kt2 = 0; kt2 < 2; ++kt2) {       // two 32-key halves
            // ---- seed C = C2*(q2 + k2): key(reg,hi) = kt2*32 + 8*(reg>>2) + 4*hi + (reg&3)
            f32x16 sc;
            #pragma unroll
            for (int g = 0; g < 4; ++g) {
                floatx4 kv = *(const floatx4*)&k2c[kt2 * 32 + g * 8 + 4 * hi];
                sc[4 * g + 0] = q2s + kv[0];
                sc[4 * g + 1] = q2s + kv[1];
                sc[4 * g + 2] = q2s + kv[2];
                sc[4 * g + 3] = q2s + kv[3];
            }
            // ---- QK^T: A = K rows (m=keys, l31), B = Q (n=q, l31) -> sc = C2*d2
            #pragma unroll
            for (int kk = 0; kk < 4; ++kk) {
                short8 kf = *(const short8*)
                    &Kt[(kt2 * 32 + l31) * 64 + (((kk * 2 + hi) ^ s7) << 3)];
                sc = __builtin_amdgcn_mfma_f32_32x32x16_bf16(kf, qf[kk], sc, 0, 0, 0);
            }
            // ---- transform + pack 4 keys -> one ds_write_b64 per g
            #pragma unroll
            for (int g = 0; g < 4; ++g) {
                unsigned u[4];
                #pragma unroll
                for (int c = 0; c < 4; ++c) {
                    float d2s = fmaxf(sc[4 * g + c], 0.f);     // C2 * d2
                    float wgt = FEXP2(-FSQRT(d2s));            // exp(-dist)
                    // expm1(wgt) quadratic; rel err < 2e-6 off-diagonal
                    float pv = wgt * fmaf(wgt, 0.5f, 1.f);
                    dsl += pv;
                    union { float f; unsigned q; } vv; vv.f = pv; u[c] = vv.q;
                }
                uintx2 pr;
                pr.x = pkbf(u[1], u[0]);
                pr.y = pkbf(u[3], u[2]);
                // P[q=l31][key]: chunk (kt2*4+g) ^ (q&7), 8B half per hi
                *(uintx2*)&Pw[l31 * 64 + (((kt2 * 4 + g) ^ s7) << 3) + hi * 4] = pr;
            }
            // ---- P'V for this half's two 16-key sub-tiles (in-order DS pipe:
            // per-wave RAW through LDS needs no barrier — r15/r17 precedent)
            #pragma unroll
            for (int kh = 0; kh < 2; ++kh) {
                int ktl = kt2 * 2 + kh;
                short8 pf = *(const short8*)
                    &Pw[l31 * 64 + (((ktl * 2 + hi) ^ s7) << 3)];
                #pragma unroll
                for (int dt = 0; dt < 2; ++dt) {
                    short8 vf = *(const short8*)
                        &Vv[(dt * 32 + l31) * 64 + (((ktl * 2 + hi) ^ s7) << 3)];
                    acc[dt] = __builtin_amdgcn_mfma_f32_32x32x16_bf16(pf, vf, acc[dt], 0, 0, 0);
                }
            }
        }
    };

    // prologue + double-buffered main loop (8 tiles of 64 keys)
    stage(0, t00);
    #pragma unroll 1
    for (int itp = 0; itp < 4; ++itp) {
        const int t0e = t00 + itp * 128;
        __syncthreads();                 // even tile DMA drained
        stage(1, t0e + 64);              // prefetch odd tile under compute
        compute(0);
        __syncthreads();                 // odd tile DMA drained
        if (itp < 3) stage(0, t0e + 128);
        compute(1);
    }

    // ---- partial epilogue ----
    dsl += __shfl_xor(dsl, 32);          // lane and lane^32 hold complementary keys
    unsigned short* nb = nbuf + (size_t)ts * (BATCH * SEQ * DIM);
    #pragma unroll
    for (int dt = 0; dt < 2; ++dt) {
        #pragma unroll
        for (int g = 0; g < 4; ++g) {
            #pragma unroll
            for (int c = 0; c < 4; ++c) {
                int q = g * 8 + 4 * hi + c;          // C-row of reg 4g+c
                nb[((size_t)(b * SEQ + qrow0 + q)) * DIM + dt * 32 + l31] =
                    f2bf(acc[dt][4 * g + c]);
            }
        }
    }
    if (hi == 0)
        dbuf[ts * (BATCH * SEQ) + b * SEQ + qrow0 + l31] = dsl;
}

// ---- finalize: out = (sum_ts nbuf + csum) / (S + sum_ts dbuf) --------------
__global__ __launch_bounds__(256) void finalize(
        const unsigned short* __restrict__ nbuf, const float* __restrict__ dbuf,
        const float* __restrict__ csum_part, float* __restrict__ out) {
    __shared__ float psh[4][64];
    __shared__ float csh[64];
    int bid = blockIdx.x, tid = threadIdx.x;     // 1024 blocks; 16 rows/block
    int b = bid >> 7;                            // all rows in a block share b
    {
        int g = tid >> 6, d = tid & 63;
        float cp = 0.f;
        #pragma unroll
        for (int p = 0; p < 8; ++p)
            cp += csum_part[(b * 32 + g * 8 + p) * 64 + d];
        psh[g][d] = cp;
    }
    __syncthreads();
    if (tid < 64)
        csh[tid] = psh[0][tid] + psh[1][tid] + psh[2][tid] + psh[3][tid];
    __syncthreads();

    int gid = bid * 256 + tid;                   // one float4 of d per thread
    int row = gid >> 4;                          // b*SEQ + s
    int dq  = gid & 15;
    float den = 2048.f;
    #pragma unroll
    for (int t = 0; t < TSPLIT; ++t) den += dbuf[t * (BATCH * SEQ) + row];
    float rcp = 1.f / den;
    float4 n = *(const float4*)&csh[dq * 4];
    #pragma unroll
    for (int t = 0; t < TSPLIT; ++t) {
        ushort4 p = *(const ushort4*)(nbuf + (size_t)t * (BATCH * SEQ * DIM)
                                           + (size_t)row * DIM + dq * 4);
        n.x += bf2f(p.x); n.y += bf2f(p.y); n.z += bf2f(p.z); n.w += bf2f(p.w);
    }
    float4 o = {n.x * rcp, n.y * rcp, n.z * rcp, n.w * rcp};
    *(float4*)(out + (size_t)row * DIM + dq * 4) = o;
}

extern "C" void kernel_launch(void* const* d_in, const int* in_sizes, int n_in,
                              void* d_out, int out_size, void* d_ws, size_t ws_size,
                              hipStream_t stream) {
    const float* Q = (const float*)d_in[0];
    const float* K = (const float*)d_in[1];
    const float* V = (const float*)d_in[2];
    float* out = (float*)d_out;

    char* ws = (char*)d_ws;                       // ws_size = 256 MiB
    unsigned short* Qb = (unsigned short*)(ws);                        // 2 MB
    unsigned short* Kb = (unsigned short*)(ws + (2u << 20));           // 2 MB (swizzled)
    unsigned short* Vt = (unsigned short*)(ws + (4u << 20));           // 2 MB (swizzled)
    float* q2     = (float*)(ws + (6u << 20));                         // 64 KB
    float* k2     = (float*)(ws + (6u << 20) + (64u << 10));           // 64 KB
    float* cpart  = (float*)(ws + (6u << 20) + (128u << 10));          // 64 KB
    float* dbuf   = (float*)(ws + (6u << 20) + (192u << 10));          // 256 KB (4 splits)
    unsigned short* nbuf = (unsigned short*)(ws + (7u << 20));         // 8 MB (bf16, 4 splits)

    prep_all<<<QK_BLK + VT_BLK, 256, 0, stream>>>(
        Q, K, V, Qb, Kb, Vt, q2, k2, cpart);
    gauss_attn<<<BATCH * 16 * TSPLIT, 256, 0, stream>>>(
        Qb, Kb, Vt, q2, k2, nbuf, dbuf);
    finalize<<<(BATCH * SEQ * DIM / 4) / 256, 256, 0, stream>>>(
        nbuf, dbuf, cpart, out);
}